// Round 1
// baseline (7772.722 us; speedup 1.0000x reference)
//
#include <hip/hip_runtime.h>

typedef __attribute__((ext_vector_type(4))) float  f32x4;
typedef __attribute__((ext_vector_type(8))) short  short8;
typedef __attribute__((ext_vector_type(4))) short  short4v;

__device__ __forceinline__ float bf2f(short s){
  unsigned u = ((unsigned)(unsigned short)s) << 16;
  float f; __builtin_memcpy(&f, &u, 4); return f;
}
__device__ __forceinline__ short f2bf(float x){
  unsigned u; __builtin_memcpy(&u, &x, 4);
  u = (u + 0x7fffu + ((u >> 16) & 1u)) >> 16;
  return (short)u;
}
__device__ __forceinline__ float sigm(float x){ return 1.f / (1.f + __expf(-x)); }
__device__ __forceinline__ float ftanh(float x){ return 1.f - 2.f / (__expf(2.f * x) + 1.f); }

// ---------------------------------------------------------------------------
// Generic bf16-MFMA GEMM: C[M,N] = A[M,K] * B[K,N] + bias[N]
// A is f32 (AF32=1) or bf16 (AF32=0); C is f32 (OF32=1) or bf16 (OF32=0).
// 128x128 tile, BK=32, 256 threads (4 waves, each 64x64 via 4x4 of 16x16).
// ---------------------------------------------------------------------------
template<int AF32, int OF32>
__global__ __launch_bounds__(256) void gemm_bias(const void* __restrict__ Av,
                                                 const float* __restrict__ B,
                                                 const float* __restrict__ bias,
                                                 void* __restrict__ Cv,
                                                 int M, int N, int K)
{
  __shared__ __align__(16) short As[128 * 40];   // [row][k] pad 40 (80B, 16B-aligned)
  __shared__ __align__(16) short Bs[128 * 40];   // [n][k] transposed
  int tid  = threadIdx.x;
  int col0 = blockIdx.x * 128, row0 = blockIdx.y * 128;
  int lane = tid & 63, wave = tid >> 6;
  int wm = (wave >> 1) * 64, wn = (wave & 1) * 64;

  f32x4 acc[4][4];
  for (int mi = 0; mi < 4; mi++)
    for (int ni = 0; ni < 4; ni++)
      for (int q = 0; q < 4; q++) acc[mi][ni][q] = 0.f;

  for (int kt = 0; kt < K; kt += 32) {
    __syncthreads();
    if (AF32) {
      const float* A = (const float*)Av;
      for (int i = 0; i < 4; i++) {
        int idx = tid + i * 256;
        int r = idx >> 3, c4 = (idx & 7) << 2;
        f32x4 v = *(const f32x4*)(A + (size_t)(row0 + r) * K + kt + c4);
        short4v o;
        for (int q = 0; q < 4; q++) o[q] = f2bf(v[q]);
        *(short4v*)&As[r * 40 + c4] = o;
      }
    } else {
      const short* A = (const short*)Av;
      for (int i = 0; i < 2; i++) {
        int idx = tid + i * 256;
        int r = idx >> 2, c8 = (idx & 3) << 3;
        short8 v = *(const short8*)(A + (size_t)(row0 + r) * K + kt + c8);
        *(short8*)&As[r * 40 + c8] = v;
      }
    }
    // B tile [32][128] -> Bs[n][k]
    for (int i = 0; i < 4; i++) {
      int idx = tid + i * 256;
      int kr = idx >> 5, c4 = (idx & 31) << 2;
      f32x4 v = *(const f32x4*)(B + (size_t)(kt + kr) * N + col0 + c4);
      for (int e = 0; e < 4; e++) Bs[(c4 + e) * 40 + kr] = f2bf(v[e]);
    }
    __syncthreads();

    int fr = lane & 15, fo = (lane >> 4) << 3;
    short8 af[4], bfr[4];
    for (int mi = 0; mi < 4; mi++) af[mi]  = *(short8*)&As[(wm + mi * 16 + fr) * 40 + fo];
    for (int ni = 0; ni < 4; ni++) bfr[ni] = *(short8*)&Bs[(wn + ni * 16 + fr) * 40 + fo];
    for (int mi = 0; mi < 4; mi++)
      for (int ni = 0; ni < 4; ni++)
        acc[mi][ni] = __builtin_amdgcn_mfma_f32_16x16x32_bf16(af[mi], bfr[ni], acc[mi][ni], 0, 0, 0);
  }

  int efr = lane & 15, efrow = (lane >> 4) << 2;
  for (int ni = 0; ni < 4; ni++) {
    int col = col0 + wn + ni * 16 + efr;
    float bv = bias[col];
    for (int mi = 0; mi < 4; mi++) {
      for (int q = 0; q < 4; q++) {
        int row = row0 + wm + mi * 16 + efrow + q;
        float v = acc[mi][ni][q] + bv;
        if (OF32) ((float*)Cv)[(size_t)row * N + col] = v;
        else      ((short*)Cv)[(size_t)row * N + col] = f2bf(v);
      }
    }
  }
}

// ---------------------------------------------------------------------------
// ws = s @ atW + atW_b : [64,128]@[128,128]
// ---------------------------------------------------------------------------
__global__ __launch_bounds__(128) void att_ws_kernel(const float* __restrict__ s,
                                                     const float* __restrict__ atW,
                                                     const float* __restrict__ atWb,
                                                     float* __restrict__ ws)
{
  int b = blockIdx.x, a = threadIdx.x;
  float acc = atWb[a];
  for (int k = 0; k < 128; k++) acc += s[b * 128 + k] * atW[k * 128 + a];
  ws[b * 128 + a] = acc;
}

// ---------------------------------------------------------------------------
// One LSTM time step for all 4 scans (m0 fwd/bwd, m1 fwd/bwd).
// grid = 160 blocks x 256 threads.
//   blocks [0,128):  m0 (H=256, NHC=4), dir = b>>6, wg = b&63
//   blocks [128,160): m1 (H=128, NHC=8), dir, wg = &15
// ---------------------------------------------------------------------------
template<int H, int NHC>
__device__ __forceinline__ void scan_body(const short* __restrict__ xg,
                                          const float* __restrict__ Wh,
                                          short* __restrict__ hall,
                                          float* __restrict__ cbuf,
                                          int wg, int dir, int sidx,
                                          short* hs, float* gl)
{
  const int C = 2 * H, H4 = 4 * H, GL = 4 * NHC + 1;
  int tid = threadIdx.x;
  int t = dir ? (511 - sidx) : sidx;
  int tprev = dir ? t + 1 : t - 1;
  int j0 = wg * NHC, dircol = dir ? H : 0;

  // stage h_prev [64][H] bf16 into LDS with 8-short-block XOR swizzle
  {
    int r = tid >> 2, seg = tid & 3;
    const int segB = (H / 8) / 4;   // short8-blocks per segment
    for (int u = 0; u < segB; u++) {
      int k8 = seg * segB + u;
      short8 v;
      if (sidx != 0) {
        v = *(const short8*)(hall + ((size_t)tprev * 64 + r) * C + dircol + k8 * 8);
      } else {
        for (int q = 0; q < 8; q++) v[q] = 0;
      }
      *(short8*)&hs[r * H + ((k8 ^ (r & 7)) << 3)] = v;
    }
  }
  __syncthreads();

  int b = tid & 63;
  int g = __builtin_amdgcn_readfirstlane(tid >> 6);   // gate index, wave-uniform -> s_loads
  float acc[NHC];
#pragma unroll
  for (int jj = 0; jj < NHC; jj++) acc[jj] = 0.f;
  const float* wbase = Wh + g * H + j0;

  for (int k8 = 0; k8 < H / 8; k8++) {
    short8 hv = *(const short8*)&hs[b * H + ((k8 ^ (b & 7)) << 3)];
#pragma unroll
    for (int kk = 0; kk < 8; kk++) {
      float hf = bf2f(hv[kk]);
      const float* wrow = wbase + (k8 * 8 + kk) * H4;
#pragma unroll
      for (int jj = 0; jj < NHC; jj++) acc[jj] = __builtin_fmaf(hf, wrow[jj], acc[jj]);
    }
  }

  const short* xr = xg + ((size_t)t * 64 + b) * H4 + g * H + j0;
#pragma unroll
  for (int jj = 0; jj < NHC; jj++)
    gl[b * GL + g * NHC + jj] = acc[jj] + bf2f(xr[jj]);
  __syncthreads();

  for (int u = tid; u < 64 * NHC; u += 256) {
    int ub = u & 63, uj = u >> 6;
    float a_ = gl[ub * GL + 0 * NHC + uj];
    float i_ = gl[ub * GL + 1 * NHC + uj];
    float f_ = gl[ub * GL + 2 * NHC + uj];
    float o_ = gl[ub * GL + 3 * NHC + uj];
    int j = j0 + uj;
    float cold = (sidx != 0) ? cbuf[j * 64 + ub] : 0.f;
    float cn = ftanh(a_) * sigm(i_) + cold * sigm(f_);
    cbuf[j * 64 + ub] = cn;
    hall[((size_t)t * 64 + ub) * C + dircol + j] = f2bf(ftanh(cn) * sigm(o_));
  }
}

__global__ __launch_bounds__(256) void lstm_step_kernel(
    const short* __restrict__ xgf0, const short* __restrict__ xgb0,
    const short* __restrict__ xgf1, const short* __restrict__ xgb1,
    const float* __restrict__ fh0, const float* __restrict__ bh0,
    const float* __restrict__ fh1, const float* __restrict__ bh1,
    short* __restrict__ hall0, short* __restrict__ hall1,
    float* c00, float* c01, float* c10, float* c11, int sidx)
{
  __shared__ __align__(16) short hs[64 * 256];
  __shared__ float gl[64 * 33];
  int bx = blockIdx.x;
  if (bx < 128) {
    int dir = bx >> 6, wg = bx & 63;
    scan_body<256, 4>(dir ? xgb0 : xgf0, dir ? bh0 : fh0, hall0,
                      dir ? c01 : c00, wg, dir, sidx, hs, gl);
  } else {
    int r = bx - 128, dir = r >> 4, wg = r & 15;
    scan_body<128, 8>(dir ? xgb1 : xgf1, dir ? bh1 : fh1, hall1,
                      dir ? c11 : c10, wg, dir, sidx, hs, gl);
  }
}

// ---------------------------------------------------------------------------
// logits[r] = tanh(vh[r,:] + ws[b,:]) . atw + atw_b   (one wave per row)
// ---------------------------------------------------------------------------
__global__ __launch_bounds__(256) void logits_kernel(const float* __restrict__ vh,
                                                     const float* __restrict__ ws,
                                                     const float* __restrict__ atw,
                                                     const float* __restrict__ atwb,
                                                     float* __restrict__ lg)
{
  int wid  = (int)((blockIdx.x * 256 + threadIdx.x) >> 6);
  int lane = threadIdx.x & 63;
  if (wid >= 32768) return;
  int b = wid & 63;
  float x0 = vh[(size_t)wid * 128 + lane]      + ws[b * 128 + lane];
  float x1 = vh[(size_t)wid * 128 + 64 + lane] + ws[b * 128 + 64 + lane];
  float v = ftanh(x0) * atw[lane] + ftanh(x1) * atw[64 + lane];
  for (int off = 32; off; off >>= 1) v += __shfl_down(v, off);
  if (lane == 0) lg[wid] = v + atwb[0];
}

// ---------------------------------------------------------------------------
// Per-batch softmax over T + context:  ctx[b,c] = (1/T) sum_t softmax(lg)_t * h[t,b,c]
// ---------------------------------------------------------------------------
__global__ __launch_bounds__(256) void softmax_ctx(const float* __restrict__ lg,
                                                   const short* __restrict__ hall,
                                                   float* __restrict__ ctx, int C)
{
  int b = blockIdx.x, tid = threadIdx.x, lane = tid & 63, wv = tid >> 6;
  __shared__ float ebuf[512];
  __shared__ float red[8];
  float l0 = lg[tid * 64 + b];
  float l1 = lg[(tid + 256) * 64 + b];
  float m = fmaxf(l0, l1);
  for (int o = 32; o; o >>= 1) m = fmaxf(m, __shfl_xor(m, o));
  if (lane == 0) red[wv] = m;
  __syncthreads();
  m = fmaxf(fmaxf(red[0], red[1]), fmaxf(red[2], red[3]));
  float e0 = __expf(l0 - m), e1 = __expf(l1 - m);
  ebuf[tid] = e0; ebuf[tid + 256] = e1;
  float sm = e0 + e1;
  for (int o = 32; o; o >>= 1) sm += __shfl_xor(sm, o);
  if (lane == 0) red[4 + wv] = sm;
  __syncthreads();
  sm = red[4] + red[5] + red[6] + red[7];
  float inv = 1.f / (sm * 512.f);
  for (int c = tid; c < C; c += 256) {
    float acc = 0.f;
    const short* hp = hall + (size_t)b * C + c;
    for (int t = 0; t < 512; t++) acc += ebuf[t] * bf2f(hp[(size_t)t * 64 * C]);
    ctx[b * C + c] = acc * inv;
  }
}

// ---------------------------------------------------------------------------
// out[b,o] = tanh(ctx0[b,:]@lgd_w0[:,o] + b0[o] + ctx1[b,:]@lgd_w1[:,o] + b1[o])
// ---------------------------------------------------------------------------
__global__ __launch_bounds__(256) void final_kernel(const float* __restrict__ ctx0,
                                                    const float* __restrict__ ctx1,
                                                    const float* __restrict__ w0,
                                                    const float* __restrict__ b0,
                                                    const float* __restrict__ w1,
                                                    const float* __restrict__ b1,
                                                    float* __restrict__ out)
{
  int b = blockIdx.x, o = threadIdx.x;
  float acc = b0[o] + b1[o];
  for (int c = 0; c < 512; c++) acc += ctx0[b * 512 + c] * w0[c * 256 + o];
  for (int c = 0; c < 256; c++) acc += ctx1[b * 256 + c] * w1[c * 256 + o];
  out[b * 256 + o] = ftanh(acc);
}

// ---------------------------------------------------------------------------
extern "C" void kernel_launch(void* const* d_in, const int* in_sizes, int n_in,
                              void* d_out, int out_size, void* d_ws, size_t ws_size,
                              hipStream_t stream)
{
  const float* x0    = (const float*)d_in[0];
  const float* x1    = (const float*)d_in[1];
  const float* sIn   = (const float*)d_in[2];
  const float* emb_w0 = (const float*)d_in[3];  const float* emb_b0 = (const float*)d_in[4];
  const float* fx_w0  = (const float*)d_in[5];  const float* fx_b0  = (const float*)d_in[6];
  const float* fh_w0  = (const float*)d_in[7];
  const float* bx_w0  = (const float*)d_in[8];  const float* bx_b0  = (const float*)d_in[9];
  const float* bh_w0  = (const float*)d_in[10];
  const float* atV_w0 = (const float*)d_in[11]; const float* atV_b0 = (const float*)d_in[12];
  const float* atW_w0 = (const float*)d_in[13]; const float* atW_b0 = (const float*)d_in[14];
  const float* atw_w0 = (const float*)d_in[15]; const float* atw_b0 = (const float*)d_in[16];
  const float* lgd_w0 = (const float*)d_in[17]; const float* lgd_b0 = (const float*)d_in[18];
  const float* emb_w1 = (const float*)d_in[19]; const float* emb_b1 = (const float*)d_in[20];
  const float* fx_w1  = (const float*)d_in[21]; const float* fx_b1  = (const float*)d_in[22];
  const float* fh_w1  = (const float*)d_in[23];
  const float* bx_w1  = (const float*)d_in[24]; const float* bx_b1  = (const float*)d_in[25];
  const float* bh_w1  = (const float*)d_in[26];
  const float* atV_w1 = (const float*)d_in[27]; const float* atV_b1 = (const float*)d_in[28];
  const float* atW_w1 = (const float*)d_in[29]; const float* atW_b1 = (const float*)d_in[30];
  const float* atw_w1 = (const float*)d_in[31]; const float* atw_b1 = (const float*)d_in[32];
  const float* lgd_w1 = (const float*)d_in[33]; const float* lgd_b1 = (const float*)d_in[34];
  float* out = (float*)d_out;

  char* wp = (char*)d_ws;
  auto alloc = [&](size_t bytes) -> void* {
    void* p = wp; wp += (bytes + 255) & ~(size_t)255; return p;
  };
  short* h0_0  = (short*)alloc(32768ull * 512 * 2);
  short* h0_1  = (short*)alloc(32768ull * 128 * 2);
  short* xgf0  = (short*)alloc(32768ull * 1024 * 2);
  short* xgb0  = (short*)alloc(32768ull * 1024 * 2);
  short* xgf1  = (short*)alloc(32768ull * 512 * 2);
  short* xgb1  = (short*)alloc(32768ull * 512 * 2);
  short* hall0 = (short*)alloc(32768ull * 512 * 2);
  short* hall1 = (short*)alloc(32768ull * 256 * 2);
  float* c00   = (float*)alloc(256 * 64 * 4);
  float* c01   = (float*)alloc(256 * 64 * 4);
  float* c10   = (float*)alloc(128 * 64 * 4);
  float* c11   = (float*)alloc(128 * 64 * 4);
  float* vh0   = (float*)alloc(32768ull * 128 * 4);
  float* vh1   = (float*)alloc(32768ull * 128 * 4);
  float* wsb0  = (float*)alloc(64 * 128 * 4);
  float* wsb1  = (float*)alloc(64 * 128 * 4);
  float* lg0   = (float*)alloc(32768 * 4);
  float* lg1   = (float*)alloc(32768 * 4);
  float* ctx0  = (float*)alloc(64 * 512 * 4);
  float* ctx1  = (float*)alloc(64 * 256 * 4);

  // embeddings (f32 in, bf16 out)
  gemm_bias<1, 0><<<dim3(4, 256), 256, 0, stream>>>(x0, emb_w0, emb_b0, h0_0, 32768, 512, 2048);
  gemm_bias<1, 0><<<dim3(1, 256), 256, 0, stream>>>(x1, emb_w1, emb_b1, h0_1, 32768, 128, 128);
  // input projections (bf16 in, bf16 out)
  gemm_bias<0, 0><<<dim3(8, 256), 256, 0, stream>>>(h0_0, fx_w0, fx_b0, xgf0, 32768, 1024, 512);
  gemm_bias<0, 0><<<dim3(8, 256), 256, 0, stream>>>(h0_0, bx_w0, bx_b0, xgb0, 32768, 1024, 512);
  gemm_bias<0, 0><<<dim3(4, 256), 256, 0, stream>>>(h0_1, fx_w1, fx_b1, xgf1, 32768, 512, 128);
  gemm_bias<0, 0><<<dim3(4, 256), 256, 0, stream>>>(h0_1, bx_w1, bx_b1, xgb1, 32768, 512, 128);
  // attention s-projection
  att_ws_kernel<<<64, 128, 0, stream>>>(sIn, atW_w0, atW_b0, wsb0);
  att_ws_kernel<<<64, 128, 0, stream>>>(sIn, atW_w1, atW_b1, wsb1);
  // recurrent scans: 512 sequential steps (kernel boundary = global sync)
  for (int sidx = 0; sidx < 512; ++sidx)
    lstm_step_kernel<<<160, 256, 0, stream>>>(xgf0, xgb0, xgf1, xgb1,
                                              fh_w0, bh_w0, fh_w1, bh_w1,
                                              hall0, hall1, c00, c01, c10, c11, sidx);
  // attention
  gemm_bias<0, 1><<<dim3(1, 256), 256, 0, stream>>>(hall0, atV_w0, atV_b0, vh0, 32768, 128, 512);
  gemm_bias<0, 1><<<dim3(1, 256), 256, 0, stream>>>(hall1, atV_w1, atV_b1, vh1, 32768, 128, 256);
  logits_kernel<<<8192, 256, 0, stream>>>(vh0, wsb0, atw_w0, atw_b0, lg0);
  logits_kernel<<<8192, 256, 0, stream>>>(vh1, wsb1, atw_w1, atw_b1, lg1);
  softmax_ctx<<<64, 256, 0, stream>>>(lg0, hall0, ctx0, 512);
  softmax_ctx<<<64, 256, 0, stream>>>(lg1, hall1, ctx1, 256);
  final_kernel<<<64, 256, 0, stream>>>(ctx0, ctx1, lgd_w0, lgd_b0, lgd_w1, lgd_b1, out);
}

// Round 2
// 4769.083 us; speedup vs baseline: 1.6298x; 1.6298x over previous
//
#include <hip/hip_runtime.h>

typedef __attribute__((ext_vector_type(4))) float  f32x4;
typedef __attribute__((ext_vector_type(8))) short  short8;
typedef __attribute__((ext_vector_type(4))) short  short4v;

union U8 { unsigned long long u[2]; short8 s; };

__device__ __forceinline__ float bf2f(short s){
  unsigned u = ((unsigned)(unsigned short)s) << 16;
  float f; __builtin_memcpy(&f, &u, 4); return f;
}
__device__ __forceinline__ short f2bf(float x){
  unsigned u; __builtin_memcpy(&u, &x, 4);
  u = (u + 0x7fffu + ((u >> 16) & 1u)) >> 16;
  return (short)u;
}
__device__ __forceinline__ float sigm(float x){ return 1.f / (1.f + __expf(-x)); }
__device__ __forceinline__ float ftanh(float x){ return 1.f - 2.f / (__expf(2.f * x) + 1.f); }

// ---------------------------------------------------------------------------
// Generic bf16-MFMA GEMM: C[M,N] = A[M,K] * B[K,N] + bias[N]
// ---------------------------------------------------------------------------
template<int AF32, int OF32>
__global__ __launch_bounds__(256) void gemm_bias(const void* __restrict__ Av,
                                                 const float* __restrict__ B,
                                                 const float* __restrict__ bias,
                                                 void* __restrict__ Cv,
                                                 int M, int N, int K)
{
  __shared__ __align__(16) short As[128 * 40];
  __shared__ __align__(16) short Bs[128 * 40];
  int tid  = threadIdx.x;
  int col0 = blockIdx.x * 128, row0 = blockIdx.y * 128;
  int lane = tid & 63, wave = tid >> 6;
  int wm = (wave >> 1) * 64, wn = (wave & 1) * 64;

  f32x4 acc[4][4];
  for (int mi = 0; mi < 4; mi++)
    for (int ni = 0; ni < 4; ni++)
      for (int q = 0; q < 4; q++) acc[mi][ni][q] = 0.f;

  for (int kt = 0; kt < K; kt += 32) {
    __syncthreads();
    if (AF32) {
      const float* A = (const float*)Av;
      for (int i = 0; i < 4; i++) {
        int idx = tid + i * 256;
        int r = idx >> 3, c4 = (idx & 7) << 2;
        f32x4 v = *(const f32x4*)(A + (size_t)(row0 + r) * K + kt + c4);
        short4v o;
        for (int q = 0; q < 4; q++) o[q] = f2bf(v[q]);
        *(short4v*)&As[r * 40 + c4] = o;
      }
    } else {
      const short* A = (const short*)Av;
      for (int i = 0; i < 2; i++) {
        int idx = tid + i * 256;
        int r = idx >> 2, c8 = (idx & 3) << 3;
        short8 v = *(const short8*)(A + (size_t)(row0 + r) * K + kt + c8);
        *(short8*)&As[r * 40 + c8] = v;
      }
    }
    for (int i = 0; i < 4; i++) {
      int idx = tid + i * 256;
      int kr = idx >> 5, c4 = (idx & 31) << 2;
      f32x4 v = *(const f32x4*)(B + (size_t)(kt + kr) * N + col0 + c4);
      for (int e = 0; e < 4; e++) Bs[(c4 + e) * 40 + kr] = f2bf(v[e]);
    }
    __syncthreads();

    int fr = lane & 15, fo = (lane >> 4) << 3;
    short8 af[4], bfr[4];
    for (int mi = 0; mi < 4; mi++) af[mi]  = *(short8*)&As[(wm + mi * 16 + fr) * 40 + fo];
    for (int ni = 0; ni < 4; ni++) bfr[ni] = *(short8*)&Bs[(wn + ni * 16 + fr) * 40 + fo];
    for (int mi = 0; mi < 4; mi++)
      for (int ni = 0; ni < 4; ni++)
        acc[mi][ni] = __builtin_amdgcn_mfma_f32_16x16x32_bf16(af[mi], bfr[ni], acc[mi][ni], 0, 0, 0);
  }

  int efr = lane & 15, efrow = (lane >> 4) << 2;
  for (int ni = 0; ni < 4; ni++) {
    int col = col0 + wn + ni * 16 + efr;
    float bv = bias[col];
    for (int mi = 0; mi < 4; mi++) {
      for (int q = 0; q < 4; q++) {
        int row = row0 + wm + mi * 16 + efrow + q;
        float v = acc[mi][ni][q] + bv;
        if (OF32) ((float*)Cv)[(size_t)row * N + col] = v;
        else      ((short*)Cv)[(size_t)row * N + col] = f2bf(v);
      }
    }
  }
}

// ---------------------------------------------------------------------------
// ws = s @ atW + atW_b
// ---------------------------------------------------------------------------
__global__ __launch_bounds__(128) void att_ws_kernel(const float* __restrict__ s,
                                                     const float* __restrict__ atW,
                                                     const float* __restrict__ atWb,
                                                     float* __restrict__ ws)
{
  int b = blockIdx.x, a = threadIdx.x;
  float acc = atWb[a];
  for (int k = 0; k < 128; k++) acc += s[b * 128 + k] * atW[k * 128 + a];
  ws[b * 128 + a] = acc;
}

// ---------------------------------------------------------------------------
// Persistent bidirectional-LSTM scan. One launch runs all 512 steps.
// 96 blocks x 256 threads: bx<64 -> m0 (H=256, 32 blocks/dir), else m1
// (H=128, 16 blocks/dir). Each block owns 32 gate-columns (8 j x 4 gates)
// for all 64 batches. Weights live in registers as MFMA B-fragments.
// h is exchanged through IC via agent-scope atomics (bypasses per-XCD L2).
// Per-scan grid barrier: monotonic counter, zeroed by hipMemsetAsync per call.
// ---------------------------------------------------------------------------
template<int H>
__device__ __forceinline__ void persistent_scan(
    const short* __restrict__ xg, const float* __restrict__ Wh,
    short* __restrict__ hall, int* __restrict__ ctr, int NB,
    int wg, int dir, float* gl)
{
  const int C = 2 * H, H4 = 4 * H, KB = H / 32;
  int tid = threadIdx.x, lane = tid & 63, w = tid >> 6;
  int j0 = wg * 8, dircol = dir ? H : 0;
  int n = lane & 15, ko = (lane >> 4) << 3;

  // --- preload weight fragments (once): bw[nt][kb], col = g*H + j0 + nt*4 + jj
  short8 bw[2][KB];
  for (int nt = 0; nt < 2; nt++) {
    int col = (n >> 2) * H + j0 + nt * 4 + (n & 3);
    for (int kb = 0; kb < KB; kb++)
      for (int e = 0; e < 8; e++)
        bw[nt][kb][e] = f2bf(Wh[(size_t)(kb * 32 + ko + e) * H4 + col]);
  }

  int batch0 = w * 16 + ((lane >> 4) << 2);  // C-frag rows (+q)
  int rowA   = w * 16 + n;                   // A-frag row = batch
  int eb = tid >> 2, ejp = tid & 3;          // epilogue (batch, j-pair)
  float c0 = 0.f, c1 = 0.f;

  // prefetch xg for step 0
  int t = dir ? 511 : 0;
  short xgr[2][4];
  for (int nt = 0; nt < 2; nt++) {
    int col = (n >> 2) * H + j0 + nt * 4 + (n & 3);
    for (int q = 0; q < 4; q++)
      xgr[nt][q] = xg[(size_t)(t * 64 + batch0 + q) * H4 + col];
  }

  for (int s = 0; s < 512; s++) {
    t = dir ? 511 - s : s;
    f32x4 acc[2];
    for (int q = 0; q < 4; q++) { acc[0][q] = 0.f; acc[1][q] = 0.f; }

    if (s > 0) {
      int tprev = dir ? t + 1 : t - 1;
      unsigned long long* hb = (unsigned long long*)(hall + ((size_t)tprev * 64 + rowA) * C + dircol);
      for (int kb = 0; kb < KB; kb++) {
        U8 u;
        int base = (kb * 32 + ko) >> 2;
        u.u[0] = __hip_atomic_load(hb + base,     __ATOMIC_RELAXED, __HIP_MEMORY_SCOPE_AGENT);
        u.u[1] = __hip_atomic_load(hb + base + 1, __ATOMIC_RELAXED, __HIP_MEMORY_SCOPE_AGENT);
        acc[0] = __builtin_amdgcn_mfma_f32_16x16x32_bf16(u.s, bw[0][kb], acc[0], 0, 0, 0);
        acc[1] = __builtin_amdgcn_mfma_f32_16x16x32_bf16(u.s, bw[1][kb], acc[1], 0, 0, 0);
      }
    }

    // C-frag + xg -> gl[batch][g*8 + j]
    for (int nt = 0; nt < 2; nt++) {
      int gcol = (n >> 2) * 8 + nt * 4 + (n & 3);
      for (int q = 0; q < 4; q++)
        gl[(batch0 + q) * 33 + gcol] = acc[nt][q] + bf2f(xgr[nt][q]);
    }
    __syncthreads();

    // gate fusion: thread -> (eb, j = ejp*2 + {0,1}); c in registers
    {
      const float* gb = gl + eb * 33 + ejp * 2;
      float a0 = gb[0],  a1 = gb[1];
      float i0 = gb[8],  i1 = gb[9];
      float f0 = gb[16], f1 = gb[17];
      float o0 = gb[24], o1 = gb[25];
      c0 = ftanh(a0) * sigm(i0) + c0 * sigm(f0);
      c1 = ftanh(a1) * sigm(i1) + c1 * sigm(f1);
      unsigned h0 = (unsigned short)f2bf(ftanh(c0) * sigm(o0));
      unsigned h1 = (unsigned short)f2bf(ftanh(c1) * sigm(o1));
      int hv = (int)(h0 | (h1 << 16));
      __hip_atomic_store((int*)(hall + ((size_t)t * 64 + eb) * C + dircol + j0 + ejp * 2), hv,
                         __ATOMIC_RELAXED, __HIP_MEMORY_SCOPE_AGENT);
    }

    if (s < 511) {
      // prefetch next step's xg (overlaps the barrier spin)
      int tn = dir ? t - 1 : t + 1;
      for (int nt = 0; nt < 2; nt++) {
        int col = (n >> 2) * H + j0 + nt * 4 + (n & 3);
        for (int q = 0; q < 4; q++)
          xgr[nt][q] = xg[(size_t)(tn * 64 + batch0 + q) * H4 + col];
      }
      __syncthreads();   // all h-stores issued & drained (vmcnt0 at barrier)
      if (tid == 0) {
        __hip_atomic_fetch_add(ctr, 1, __ATOMIC_RELEASE, __HIP_MEMORY_SCOPE_AGENT);
        int target = (s + 1) * NB;
        while (__hip_atomic_load(ctr, __ATOMIC_ACQUIRE, __HIP_MEMORY_SCOPE_AGENT) < target)
          __builtin_amdgcn_s_sleep(2);
      }
      __syncthreads();
    }
  }
}

__global__ __launch_bounds__(256) void lstm_persistent(
    const short* __restrict__ xgf0, const short* __restrict__ xgb0,
    const short* __restrict__ xgf1, const short* __restrict__ xgb1,
    const float* __restrict__ fh0, const float* __restrict__ bh0,
    const float* __restrict__ fh1, const float* __restrict__ bh1,
    short* __restrict__ hall0, short* __restrict__ hall1, int* __restrict__ bar)
{
  __shared__ float gl[64 * 33];
  int bx = blockIdx.x;
  if (bx < 64) {
    int dir = bx >> 5, wg = bx & 31;
    persistent_scan<256>(dir ? xgb0 : xgf0, dir ? bh0 : fh0, hall0,
                         bar + (dir ? 64 : 0), 32, wg, dir, gl);
  } else {
    int r = bx - 64, dir = r >> 4, wg = r & 15;
    persistent_scan<128>(dir ? xgb1 : xgf1, dir ? bh1 : fh1, hall1,
                         bar + 128 + (dir ? 64 : 0), 16, wg, dir, gl);
  }
}

// ---------------------------------------------------------------------------
// logits[r] = tanh(vh[r,:] + ws[b,:]) . atw + atw_b
// ---------------------------------------------------------------------------
__global__ __launch_bounds__(256) void logits_kernel(const float* __restrict__ vh,
                                                     const float* __restrict__ ws,
                                                     const float* __restrict__ atw,
                                                     const float* __restrict__ atwb,
                                                     float* __restrict__ lg)
{
  int wid  = (int)((blockIdx.x * 256 + threadIdx.x) >> 6);
  int lane = threadIdx.x & 63;
  if (wid >= 32768) return;
  int b = wid & 63;
  float x0 = vh[(size_t)wid * 128 + lane]      + ws[b * 128 + lane];
  float x1 = vh[(size_t)wid * 128 + 64 + lane] + ws[b * 128 + 64 + lane];
  float v = ftanh(x0) * atw[lane] + ftanh(x1) * atw[64 + lane];
  for (int off = 32; off; off >>= 1) v += __shfl_down(v, off);
  if (lane == 0) lg[wid] = v + atwb[0];
}

// ---------------------------------------------------------------------------
// Per-batch softmax over T + context
// ---------------------------------------------------------------------------
__global__ __launch_bounds__(256) void softmax_ctx(const float* __restrict__ lg,
                                                   const short* __restrict__ hall,
                                                   float* __restrict__ ctx, int C)
{
  int b = blockIdx.x, tid = threadIdx.x, lane = tid & 63, wv = tid >> 6;
  __shared__ float ebuf[512];
  __shared__ float red[8];
  float l0 = lg[tid * 64 + b];
  float l1 = lg[(tid + 256) * 64 + b];
  float m = fmaxf(l0, l1);
  for (int o = 32; o; o >>= 1) m = fmaxf(m, __shfl_xor(m, o));
  if (lane == 0) red[wv] = m;
  __syncthreads();
  m = fmaxf(fmaxf(red[0], red[1]), fmaxf(red[2], red[3]));
  float e0 = __expf(l0 - m), e1 = __expf(l1 - m);
  ebuf[tid] = e0; ebuf[tid + 256] = e1;
  float sm = e0 + e1;
  for (int o = 32; o; o >>= 1) sm += __shfl_xor(sm, o);
  if (lane == 0) red[4 + wv] = sm;
  __syncthreads();
  sm = red[4] + red[5] + red[6] + red[7];
  float inv = 1.f / (sm * 512.f);
  for (int c = tid; c < C; c += 256) {
    float acc = 0.f;
    const short* hp = hall + (size_t)b * C + c;
    for (int t = 0; t < 512; t++) acc += ebuf[t] * bf2f(hp[(size_t)t * 64 * C]);
    ctx[b * C + c] = acc * inv;
  }
}

// ---------------------------------------------------------------------------
__global__ __launch_bounds__(256) void final_kernel(const float* __restrict__ ctx0,
                                                    const float* __restrict__ ctx1,
                                                    const float* __restrict__ w0,
                                                    const float* __restrict__ b0,
                                                    const float* __restrict__ w1,
                                                    const float* __restrict__ b1,
                                                    float* __restrict__ out)
{
  int b = blockIdx.x, o = threadIdx.x;
  float acc = b0[o] + b1[o];
  for (int c = 0; c < 512; c++) acc += ctx0[b * 512 + c] * w0[c * 256 + o];
  for (int c = 0; c < 256; c++) acc += ctx1[b * 256 + c] * w1[c * 256 + o];
  out[b * 256 + o] = ftanh(acc);
}

// ---------------------------------------------------------------------------
extern "C" void kernel_launch(void* const* d_in, const int* in_sizes, int n_in,
                              void* d_out, int out_size, void* d_ws, size_t ws_size,
                              hipStream_t stream)
{
  const float* x0    = (const float*)d_in[0];
  const float* x1    = (const float*)d_in[1];
  const float* sIn   = (const float*)d_in[2];
  const float* emb_w0 = (const float*)d_in[3];  const float* emb_b0 = (const float*)d_in[4];
  const float* fx_w0  = (const float*)d_in[5];  const float* fx_b0  = (const float*)d_in[6];
  const float* fh_w0  = (const float*)d_in[7];
  const float* bx_w0  = (const float*)d_in[8];  const float* bx_b0  = (const float*)d_in[9];
  const float* bh_w0  = (const float*)d_in[10];
  const float* atV_w0 = (const float*)d_in[11]; const float* atV_b0 = (const float*)d_in[12];
  const float* atW_w0 = (const float*)d_in[13]; const float* atW_b0 = (const float*)d_in[14];
  const float* atw_w0 = (const float*)d_in[15]; const float* atw_b0 = (const float*)d_in[16];
  const float* lgd_w0 = (const float*)d_in[17]; const float* lgd_b0 = (const float*)d_in[18];
  const float* emb_w1 = (const float*)d_in[19]; const float* emb_b1 = (const float*)d_in[20];
  const float* fx_w1  = (const float*)d_in[21]; const float* fx_b1  = (const float*)d_in[22];
  const float* fh_w1  = (const float*)d_in[23];
  const float* bx_w1  = (const float*)d_in[24]; const float* bx_b1  = (const float*)d_in[25];
  const float* bh_w1  = (const float*)d_in[26];
  const float* atV_w1 = (const float*)d_in[27]; const float* atV_b1 = (const float*)d_in[28];
  const float* atW_w1 = (const float*)d_in[29]; const float* atW_b1 = (const float*)d_in[30];
  const float* atw_w1 = (const float*)d_in[31]; const float* atw_b1 = (const float*)d_in[32];
  const float* lgd_w1 = (const float*)d_in[33]; const float* lgd_b1 = (const float*)d_in[34];
  float* out = (float*)d_out;

  char* wp = (char*)d_ws;
  auto alloc = [&](size_t bytes) -> void* {
    void* p = wp; wp += (bytes + 255) & ~(size_t)255; return p;
  };
  int*   bar   = (int*)alloc(1024);                 // 4 barrier counters, 256B apart
  short* h0_0  = (short*)alloc(32768ull * 512 * 2);
  short* h0_1  = (short*)alloc(32768ull * 128 * 2);
  short* xgf0  = (short*)alloc(32768ull * 1024 * 2);
  short* xgb0  = (short*)alloc(32768ull * 1024 * 2);
  short* xgf1  = (short*)alloc(32768ull * 512 * 2);
  short* xgb1  = (short*)alloc(32768ull * 512 * 2);
  short* hall0 = (short*)alloc(32768ull * 512 * 2);
  short* hall1 = (short*)alloc(32768ull * 256 * 2);
  float* vh0   = (float*)alloc(32768ull * 128 * 4);
  float* vh1   = (float*)alloc(32768ull * 128 * 4);
  float* wsb0  = (float*)alloc(64 * 128 * 4);
  float* wsb1  = (float*)alloc(64 * 128 * 4);
  float* lg0   = (float*)alloc(32768 * 4);
  float* lg1   = (float*)alloc(32768 * 4);
  float* ctx0  = (float*)alloc(64 * 512 * 4);
  float* ctx1  = (float*)alloc(64 * 256 * 4);

  // embeddings (f32 in, bf16 out)
  gemm_bias<1, 0><<<dim3(4, 256), 256, 0, stream>>>(x0, emb_w0, emb_b0, h0_0, 32768, 512, 2048);
  gemm_bias<1, 0><<<dim3(1, 256), 256, 0, stream>>>(x1, emb_w1, emb_b1, h0_1, 32768, 128, 128);
  // input projections (bf16 in, bf16 out)
  gemm_bias<0, 0><<<dim3(8, 256), 256, 0, stream>>>(h0_0, fx_w0, fx_b0, xgf0, 32768, 1024, 512);
  gemm_bias<0, 0><<<dim3(8, 256), 256, 0, stream>>>(h0_0, bx_w0, bx_b0, xgb0, 32768, 1024, 512);
  gemm_bias<0, 0><<<dim3(4, 256), 256, 0, stream>>>(h0_1, fx_w1, fx_b1, xgf1, 32768, 512, 128);
  gemm_bias<0, 0><<<dim3(4, 256), 256, 0, stream>>>(h0_1, bx_w1, bx_b1, xgb1, 32768, 512, 128);
  // attention s-projection
  att_ws_kernel<<<64, 128, 0, stream>>>(sIn, atW_w0, atW_b0, wsb0);
  att_ws_kernel<<<64, 128, 0, stream>>>(sIn, atW_w1, atW_b1, wsb1);

  // persistent bidirectional LSTM scans (one dispatch, 512 internal steps)
  hipMemsetAsync(bar, 0, 1024, stream);
  lstm_persistent<<<96, 256, 0, stream>>>(xgf0, xgb0, xgf1, xgb1,
                                          fh_w0, bh_w0, fh_w1, bh_w1,
                                          hall0, hall1, bar);

  // attention
  gemm_bias<0, 1><<<dim3(1, 256), 256, 0, stream>>>(hall0, atV_w0, atV_b0, vh0, 32768, 128, 512);
  gemm_bias<0, 1><<<dim3(1, 256), 256, 0, stream>>>(hall1, atV_w1, atV_b1, vh1, 32768, 128, 256);
  logits_kernel<<<8192, 256, 0, stream>>>(vh0, wsb0, atw_w0, atw_b0, lg0);
  logits_kernel<<<8192, 256, 0, stream>>>(vh1, wsb1, atw_w1, atw_b1, lg1);
  softmax_ctx<<<64, 256, 0, stream>>>(lg0, hall0, ctx0, 512);
  softmax_ctx<<<64, 256, 0, stream>>>(lg1, hall1, ctx1, 256);
  final_kernel<<<64, 256, 0, stream>>>(ctx0, ctx1, lgd_w0, lgd_b0, lgd_w1, lgd_b1, out);
}

// Round 3
// 3469.276 us; speedup vs baseline: 2.2404x; 1.3747x over previous
//
#include <hip/hip_runtime.h>

typedef __attribute__((ext_vector_type(4))) float  f32x4;
typedef __attribute__((ext_vector_type(8))) short  short8;
typedef __attribute__((ext_vector_type(4))) short  short4v;

union U8 { unsigned long long u[2]; short8 s; };

__device__ __forceinline__ float bf2f(short s){
  unsigned u = ((unsigned)(unsigned short)s) << 16;
  float f; __builtin_memcpy(&f, &u, 4); return f;
}
__device__ __forceinline__ short f2bf(float x){
  unsigned u; __builtin_memcpy(&u, &x, 4);
  u = (u + 0x7fffu + ((u >> 16) & 1u)) >> 16;
  return (short)u;
}
__device__ __forceinline__ float sigm(float x){ return 1.f / (1.f + __expf(-x)); }
__device__ __forceinline__ float ftanh(float x){ return 1.f - 2.f / (__expf(2.f * x) + 1.f); }

// ---------------------------------------------------------------------------
// Generic bf16-MFMA GEMM: C[M,N] = A[M,K] * B[K,N] + bias[N]
// ---------------------------------------------------------------------------
template<int AF32, int OF32>
__global__ __launch_bounds__(256) void gemm_bias(const void* __restrict__ Av,
                                                 const float* __restrict__ B,
                                                 const float* __restrict__ bias,
                                                 void* __restrict__ Cv,
                                                 int M, int N, int K)
{
  __shared__ __align__(16) short As[128 * 40];
  __shared__ __align__(16) short Bs[128 * 40];
  int tid  = threadIdx.x;
  int col0 = blockIdx.x * 128, row0 = blockIdx.y * 128;
  int lane = tid & 63, wave = tid >> 6;
  int wm = (wave >> 1) * 64, wn = (wave & 1) * 64;

  f32x4 acc[4][4];
  for (int mi = 0; mi < 4; mi++)
    for (int ni = 0; ni < 4; ni++)
      for (int q = 0; q < 4; q++) acc[mi][ni][q] = 0.f;

  for (int kt = 0; kt < K; kt += 32) {
    __syncthreads();
    if (AF32) {
      const float* A = (const float*)Av;
      for (int i = 0; i < 4; i++) {
        int idx = tid + i * 256;
        int r = idx >> 3, c4 = (idx & 7) << 2;
        f32x4 v = *(const f32x4*)(A + (size_t)(row0 + r) * K + kt + c4);
        short4v o;
        for (int q = 0; q < 4; q++) o[q] = f2bf(v[q]);
        *(short4v*)&As[r * 40 + c4] = o;
      }
    } else {
      const short* A = (const short*)Av;
      for (int i = 0; i < 2; i++) {
        int idx = tid + i * 256;
        int r = idx >> 2, c8 = (idx & 3) << 3;
        short8 v = *(const short8*)(A + (size_t)(row0 + r) * K + kt + c8);
        *(short8*)&As[r * 40 + c8] = v;
      }
    }
    for (int i = 0; i < 4; i++) {
      int idx = tid + i * 256;
      int kr = idx >> 5, c4 = (idx & 31) << 2;
      f32x4 v = *(const f32x4*)(B + (size_t)(kt + kr) * N + col0 + c4);
      for (int e = 0; e < 4; e++) Bs[(c4 + e) * 40 + kr] = f2bf(v[e]);
    }
    __syncthreads();

    int fr = lane & 15, fo = (lane >> 4) << 3;
    short8 af[4], bfr[4];
    for (int mi = 0; mi < 4; mi++) af[mi]  = *(short8*)&As[(wm + mi * 16 + fr) * 40 + fo];
    for (int ni = 0; ni < 4; ni++) bfr[ni] = *(short8*)&Bs[(wn + ni * 16 + fr) * 40 + fo];
    for (int mi = 0; mi < 4; mi++)
      for (int ni = 0; ni < 4; ni++)
        acc[mi][ni] = __builtin_amdgcn_mfma_f32_16x16x32_bf16(af[mi], bfr[ni], acc[mi][ni], 0, 0, 0);
  }

  int efr = lane & 15, efrow = (lane >> 4) << 2;
  for (int ni = 0; ni < 4; ni++) {
    int col = col0 + wn + ni * 16 + efr;
    float bv = bias[col];
    for (int mi = 0; mi < 4; mi++) {
      for (int q = 0; q < 4; q++) {
        int row = row0 + wm + mi * 16 + efrow + q;
        float v = acc[mi][ni][q] + bv;
        if (OF32) ((float*)Cv)[(size_t)row * N + col] = v;
        else      ((short*)Cv)[(size_t)row * N + col] = f2bf(v);
      }
    }
  }
}

// ---------------------------------------------------------------------------
// ws = s @ atW + atW_b
// ---------------------------------------------------------------------------
__global__ __launch_bounds__(128) void att_ws_kernel(const float* __restrict__ s,
                                                     const float* __restrict__ atW,
                                                     const float* __restrict__ atWb,
                                                     float* __restrict__ ws)
{
  int b = blockIdx.x, a = threadIdx.x;
  float acc = atWb[a];
  for (int k = 0; k < 128; k++) acc += s[b * 128 + k] * atW[k * 128 + a];
  ws[b * 128 + a] = acc;
}

// ---------------------------------------------------------------------------
// Persistent bidirectional-LSTM scan. One launch runs all 512 steps.
// ALL cross-block traffic (h, barrier counters) uses RELAXED agent-scope
// atomics: the sc1 access itself is coherent at the IC; no acquire/release
// fences (those emit buffer_inv / buffer_wbl2 = full-L2 maintenance per poll,
// which was the R2 latency+overfetch wall). Ordering store->add and
// detect->load is via the vmcnt(0) drain in __syncthreads + program order.
// ---------------------------------------------------------------------------
template<int H>
__device__ __forceinline__ void persistent_scan(
    const short* __restrict__ xg, const float* __restrict__ Wh,
    short* __restrict__ hall, int* __restrict__ ctr, int NB,
    int wg, int dir, float* gl)
{
  const int C = 2 * H, H4 = 4 * H, KB = H / 32;
  int tid = threadIdx.x, lane = tid & 63, w = tid >> 6;
  int j0 = wg * 8, dircol = dir ? H : 0;
  int n = lane & 15, ko = (lane >> 4) << 3;

  // --- preload weight fragments (once): bw[nt][kb], col = g*H + j0 + nt*4 + jj
  short8 bw[2][KB];
  for (int nt = 0; nt < 2; nt++) {
    int col = (n >> 2) * H + j0 + nt * 4 + (n & 3);
    for (int kb = 0; kb < KB; kb++)
      for (int e = 0; e < 8; e++)
        bw[nt][kb][e] = f2bf(Wh[(size_t)(kb * 32 + ko + e) * H4 + col]);
  }

  int batch0 = w * 16 + ((lane >> 4) << 2);  // C-frag rows (+q)
  int rowA   = w * 16 + n;                   // A-frag row = batch
  int eb = tid >> 2, ejp = tid & 3;          // epilogue (batch, j-pair)
  float c0 = 0.f, c1 = 0.f;

  // prefetch xg for step 0
  int t = dir ? 511 : 0;
  short xgr[2][4];
  for (int nt = 0; nt < 2; nt++) {
    int col = (n >> 2) * H + j0 + nt * 4 + (n & 3);
    for (int q = 0; q < 4; q++)
      xgr[nt][q] = xg[(size_t)(t * 64 + batch0 + q) * H4 + col];
  }

  for (int s = 0; s < 512; s++) {
    t = dir ? 511 - s : s;
    f32x4 acc[2];
    for (int q = 0; q < 4; q++) { acc[0][q] = 0.f; acc[1][q] = 0.f; }

    if (s > 0) {
      int tprev = dir ? t + 1 : t - 1;
      unsigned long long* hb = (unsigned long long*)(hall + ((size_t)tprev * 64 + rowA) * C + dircol);
      for (int kb = 0; kb < KB; kb++) {
        U8 u;
        int base = (kb * 32 + ko) >> 2;
        u.u[0] = __hip_atomic_load(hb + base,     __ATOMIC_RELAXED, __HIP_MEMORY_SCOPE_AGENT);
        u.u[1] = __hip_atomic_load(hb + base + 1, __ATOMIC_RELAXED, __HIP_MEMORY_SCOPE_AGENT);
        acc[0] = __builtin_amdgcn_mfma_f32_16x16x32_bf16(u.s, bw[0][kb], acc[0], 0, 0, 0);
        acc[1] = __builtin_amdgcn_mfma_f32_16x16x32_bf16(u.s, bw[1][kb], acc[1], 0, 0, 0);
      }
    }

    // C-frag + xg -> gl[batch][g*8 + j]
    for (int nt = 0; nt < 2; nt++) {
      int gcol = (n >> 2) * 8 + nt * 4 + (n & 3);
      for (int q = 0; q < 4; q++)
        gl[(batch0 + q) * 33 + gcol] = acc[nt][q] + bf2f(xgr[nt][q]);
    }
    __syncthreads();

    // gate fusion: thread -> (eb, j = ejp*2 + {0,1}); c in registers
    {
      const float* gb = gl + eb * 33 + ejp * 2;
      float a0 = gb[0],  a1 = gb[1];
      float i0 = gb[8],  i1 = gb[9];
      float f0 = gb[16], f1 = gb[17];
      float o0 = gb[24], o1 = gb[25];
      c0 = ftanh(a0) * sigm(i0) + c0 * sigm(f0);
      c1 = ftanh(a1) * sigm(i1) + c1 * sigm(f1);
      unsigned h0 = (unsigned short)f2bf(ftanh(c0) * sigm(o0));
      unsigned h1 = (unsigned short)f2bf(ftanh(c1) * sigm(o1));
      int hv = (int)(h0 | (h1 << 16));
      __hip_atomic_store((int*)(hall + ((size_t)t * 64 + eb) * C + dircol + j0 + ejp * 2), hv,
                         __ATOMIC_RELAXED, __HIP_MEMORY_SCOPE_AGENT);
    }

    if (s < 511) {
      // prefetch next step's xg (overlaps the barrier spin)
      int tn = dir ? t - 1 : t + 1;
      for (int nt = 0; nt < 2; nt++) {
        int col = (n >> 2) * H + j0 + nt * 4 + (n & 3);
        for (int q = 0; q < 4; q++)
          xgr[nt][q] = xg[(size_t)(tn * 64 + batch0 + q) * H4 + col];
      }
      __syncthreads();   // vmcnt(0): h stores ACKed at IC before arrival add
      if (tid == 0) {
        __hip_atomic_fetch_add(ctr, 1, __ATOMIC_RELAXED, __HIP_MEMORY_SCOPE_AGENT);
        int target = (s + 1) * NB;
        while (__hip_atomic_load(ctr, __ATOMIC_RELAXED, __HIP_MEMORY_SCOPE_AGENT) < target)
          __builtin_amdgcn_s_sleep(1);
      }
      __syncthreads();
    }
  }
}

__global__ __launch_bounds__(256) void lstm_persistent(
    const short* __restrict__ xgf0, const short* __restrict__ xgb0,
    const short* __restrict__ xgf1, const short* __restrict__ xgb1,
    const float* __restrict__ fh0, const float* __restrict__ bh0,
    const float* __restrict__ fh1, const float* __restrict__ bh1,
    short* __restrict__ hall0, short* __restrict__ hall1, int* __restrict__ bar)
{
  __shared__ float gl[64 * 33];
  int bx = blockIdx.x;
  if (bx < 64) {
    int dir = bx >> 5, wg = bx & 31;
    persistent_scan<256>(dir ? xgb0 : xgf0, dir ? bh0 : fh0, hall0,
                         bar + (dir ? 64 : 0), 32, wg, dir, gl);
  } else {
    int r = bx - 64, dir = r >> 4, wg = r & 15;
    persistent_scan<128>(dir ? xgb1 : xgf1, dir ? bh1 : fh1, hall1,
                         bar + 128 + (dir ? 64 : 0), 16, wg, dir, gl);
  }
}

// ---------------------------------------------------------------------------
// logits[r] = tanh(vh[r,:] + ws[b,:]) . atw + atw_b
// ---------------------------------------------------------------------------
__global__ __launch_bounds__(256) void logits_kernel(const float* __restrict__ vh,
                                                     const float* __restrict__ ws,
                                                     const float* __restrict__ atw,
                                                     const float* __restrict__ atwb,
                                                     float* __restrict__ lg)
{
  int wid  = (int)((blockIdx.x * 256 + threadIdx.x) >> 6);
  int lane = threadIdx.x & 63;
  if (wid >= 32768) return;
  int b = wid & 63;
  float x0 = vh[(size_t)wid * 128 + lane]      + ws[b * 128 + lane];
  float x1 = vh[(size_t)wid * 128 + 64 + lane] + ws[b * 128 + 64 + lane];
  float v = ftanh(x0) * atw[lane] + ftanh(x1) * atw[64 + lane];
  for (int off = 32; off; off >>= 1) v += __shfl_down(v, off);
  if (lane == 0) lg[wid] = v + atwb[0];
}

// ---------------------------------------------------------------------------
// Per-batch softmax over T + context
// ---------------------------------------------------------------------------
__global__ __launch_bounds__(256) void softmax_ctx(const float* __restrict__ lg,
                                                   const short* __restrict__ hall,
                                                   float* __restrict__ ctx, int C)
{
  int b = blockIdx.x, tid = threadIdx.x, lane = tid & 63, wv = tid >> 6;
  __shared__ float ebuf[512];
  __shared__ float red[8];
  float l0 = lg[tid * 64 + b];
  float l1 = lg[(tid + 256) * 64 + b];
  float m = fmaxf(l0, l1);
  for (int o = 32; o; o >>= 1) m = fmaxf(m, __shfl_xor(m, o));
  if (lane == 0) red[wv] = m;
  __syncthreads();
  m = fmaxf(fmaxf(red[0], red[1]), fmaxf(red[2], red[3]));
  float e0 = __expf(l0 - m), e1 = __expf(l1 - m);
  ebuf[tid] = e0; ebuf[tid + 256] = e1;
  float sm = e0 + e1;
  for (int o = 32; o; o >>= 1) sm += __shfl_xor(sm, o);
  if (lane == 0) red[4 + wv] = sm;
  __syncthreads();
  sm = red[4] + red[5] + red[6] + red[7];
  float inv = 1.f / (sm * 512.f);
  for (int c = tid; c < C; c += 256) {
    float acc = 0.f;
    const short* hp = hall + (size_t)b * C + c;
    for (int t = 0; t < 512; t++) acc += ebuf[t] * bf2f(hp[(size_t)t * 64 * C]);
    ctx[b * C + c] = acc * inv;
  }
}

// ---------------------------------------------------------------------------
__global__ __launch_bounds__(256) void final_kernel(const float* __restrict__ ctx0,
                                                    const float* __restrict__ ctx1,
                                                    const float* __restrict__ w0,
                                                    const float* __restrict__ b0,
                                                    const float* __restrict__ w1,
                                                    const float* __restrict__ b1,
                                                    float* __restrict__ out)
{
  int b = blockIdx.x, o = threadIdx.x;
  float acc = b0[o] + b1[o];
  for (int c = 0; c < 512; c++) acc += ctx0[b * 512 + c] * w0[c * 256 + o];
  for (int c = 0; c < 256; c++) acc += ctx1[b * 256 + c] * w1[c * 256 + o];
  out[b * 256 + o] = ftanh(acc);
}

// ---------------------------------------------------------------------------
extern "C" void kernel_launch(void* const* d_in, const int* in_sizes, int n_in,
                              void* d_out, int out_size, void* d_ws, size_t ws_size,
                              hipStream_t stream)
{
  const float* x0    = (const float*)d_in[0];
  const float* x1    = (const float*)d_in[1];
  const float* sIn   = (const float*)d_in[2];
  const float* emb_w0 = (const float*)d_in[3];  const float* emb_b0 = (const float*)d_in[4];
  const float* fx_w0  = (const float*)d_in[5];  const float* fx_b0  = (const float*)d_in[6];
  const float* fh_w0  = (const float*)d_in[7];
  const float* bx_w0  = (const float*)d_in[8];  const float* bx_b0  = (const float*)d_in[9];
  const float* bh_w0  = (const float*)d_in[10];
  const float* atV_w0 = (const float*)d_in[11]; const float* atV_b0 = (const float*)d_in[12];
  const float* atW_w0 = (const float*)d_in[13]; const float* atW_b0 = (const float*)d_in[14];
  const float* atw_w0 = (const float*)d_in[15]; const float* atw_b0 = (const float*)d_in[16];
  const float* lgd_w0 = (const float*)d_in[17]; const float* lgd_b0 = (const float*)d_in[18];
  const float* emb_w1 = (const float*)d_in[19]; const float* emb_b1 = (const float*)d_in[20];
  const float* fx_w1  = (const float*)d_in[21]; const float* fx_b1  = (const float*)d_in[22];
  const float* fh_w1  = (const float*)d_in[23];
  const float* bx_w1  = (const float*)d_in[24]; const float* bx_b1  = (const float*)d_in[25];
  const float* bh_w1  = (const float*)d_in[26];
  const float* atV_w1 = (const float*)d_in[27]; const float* atV_b1 = (const float*)d_in[28];
  const float* atW_w1 = (const float*)d_in[29]; const float* atW_b1 = (const float*)d_in[30];
  const float* atw_w1 = (const float*)d_in[31]; const float* atw_b1 = (const float*)d_in[32];
  const float* lgd_w1 = (const float*)d_in[33]; const float* lgd_b1 = (const float*)d_in[34];
  float* out = (float*)d_out;

  char* wp = (char*)d_ws;
  auto alloc = [&](size_t bytes) -> void* {
    void* p = wp; wp += (bytes + 255) & ~(size_t)255; return p;
  };
  int*   bar   = (int*)alloc(1024);                 // 4 barrier counters, 256B apart
  short* h0_0  = (short*)alloc(32768ull * 512 * 2);
  short* h0_1  = (short*)alloc(32768ull * 128 * 2);
  short* xgf0  = (short*)alloc(32768ull * 1024 * 2);
  short* xgb0  = (short*)alloc(32768ull * 1024 * 2);
  short* xgf1  = (short*)alloc(32768ull * 512 * 2);
  short* xgb1  = (short*)alloc(32768ull * 512 * 2);
  short* hall0 = (short*)alloc(32768ull * 512 * 2);
  short* hall1 = (short*)alloc(32768ull * 256 * 2);
  float* vh0   = (float*)alloc(32768ull * 128 * 4);
  float* vh1   = (float*)alloc(32768ull * 128 * 4);
  float* wsb0  = (float*)alloc(64 * 128 * 4);
  float* wsb1  = (float*)alloc(64 * 128 * 4);
  float* lg0   = (float*)alloc(32768 * 4);
  float* lg1   = (float*)alloc(32768 * 4);
  float* ctx0  = (float*)alloc(64 * 512 * 4);
  float* ctx1  = (float*)alloc(64 * 256 * 4);

  // embeddings (f32 in, bf16 out)
  gemm_bias<1, 0><<<dim3(4, 256), 256, 0, stream>>>(x0, emb_w0, emb_b0, h0_0, 32768, 512, 2048);
  gemm_bias<1, 0><<<dim3(1, 256), 256, 0, stream>>>(x1, emb_w1, emb_b1, h0_1, 32768, 128, 128);
  // input projections (bf16 in, bf16 out)
  gemm_bias<0, 0><<<dim3(8, 256), 256, 0, stream>>>(h0_0, fx_w0, fx_b0, xgf0, 32768, 1024, 512);
  gemm_bias<0, 0><<<dim3(8, 256), 256, 0, stream>>>(h0_0, bx_w0, bx_b0, xgb0, 32768, 1024, 512);
  gemm_bias<0, 0><<<dim3(4, 256), 256, 0, stream>>>(h0_1, fx_w1, fx_b1, xgf1, 32768, 512, 128);
  gemm_bias<0, 0><<<dim3(4, 256), 256, 0, stream>>>(h0_1, bx_w1, bx_b1, xgb1, 32768, 512, 128);
  // attention s-projection
  att_ws_kernel<<<64, 128, 0, stream>>>(sIn, atW_w0, atW_b0, wsb0);
  att_ws_kernel<<<64, 128, 0, stream>>>(sIn, atW_w1, atW_b1, wsb1);

  // persistent bidirectional LSTM scans (one dispatch, 512 internal steps)
  hipMemsetAsync(bar, 0, 1024, stream);
  lstm_persistent<<<96, 256, 0, stream>>>(xgf0, xgb0, xgf1, xgb1,
                                          fh_w0, bh_w0, fh_w1, bh_w1,
                                          hall0, hall1, bar);

  // attention
  gemm_bias<0, 1><<<dim3(1, 256), 256, 0, stream>>>(hall0, atV_w0, atV_b0, vh0, 32768, 128, 512);
  gemm_bias<0, 1><<<dim3(1, 256), 256, 0, stream>>>(hall1, atV_w1, atV_b1, vh1, 32768, 128, 256);
  logits_kernel<<<8192, 256, 0, stream>>>(vh0, wsb0, atw_w0, atw_b0, lg0);
  logits_kernel<<<8192, 256, 0, stream>>>(vh1, wsb1, atw_w1, atw_b1, lg1);
  softmax_ctx<<<64, 256, 0, stream>>>(lg0, hall0, ctx0, 512);
  softmax_ctx<<<64, 256, 0, stream>>>(lg1, hall1, ctx1, 256);
  final_kernel<<<64, 256, 0, stream>>>(ctx0, ctx1, lgd_w0, lgd_b0, lgd_w1, lgd_b1, out);
}